// Round 10
// baseline (939.335 us; speedup 1.0000x reference)
//
#include <hip/hip_runtime.h>
#include <hip/hip_bf16.h>

#define NN 50000
#define NE 600000
#define D 128
#define NL 5

typedef __hip_bfloat16 bf16;
typedef unsigned short ushort_t;
typedef _Float16 half_t;
typedef __attribute__((ext_vector_type(8))) _Float16 half8;
typedef __attribute__((ext_vector_type(8))) short short8;
typedef __attribute__((ext_vector_type(4))) float f32x4;
typedef __attribute__((ext_vector_type(2))) float f32x2;

__device__ __forceinline__ float b2f(bf16 v) { return __bfloat162float(v); }

__device__ __forceinline__ float loadF(const void* p, long long i, int isf32) {
    if (isf32) return ((const float*)p)[i];
    return b2f(((const bf16*)p)[i]);
}

__global__ void detect_k(const void* __restrict__ atom, int* __restrict__ flag) {
    __shared__ int vote;
    if (threadIdx.x == 0) vote = 0;
    __syncthreads();
    unsigned short u = ((const unsigned short*)atom)[threadIdx.x];
    unsigned short ex = (u >> 7) & 0xFF;
    if (ex >= 0x90) atomicOr(&vote, 1);
    __syncthreads();
    if (threadIdx.x == 0) *flag = vote;
}

__global__ void zero_f(float* __restrict__ p, int n) {
    int i = blockIdx.x * 256 + threadIdx.x;
    if (i < n) p[i] = 0.f;
}
__global__ void zero_i(int* __restrict__ p, int n) {
    int i = blockIdx.x * 256 + threadIdx.x;
    if (i < n) p[i] = 0;
}

// convert + transpose weights to fp16 once per launch:
// w1t[l][n<256][k<128] = W1[l][k][n];  w2t[l][n<128][k<256] = W2[l][k][n]
__global__ void prepw_k(const void* __restrict__ W1, const void* __restrict__ W2,
                        const int* __restrict__ fl,
                        half_t* __restrict__ w1t, half_t* __restrict__ w2t) {
    int isf32 = *fl;
    int idx = blockIdx.x * 256 + threadIdx.x;
    const int per = NL * 2 * D * D;  // 163840
    if (idx < per) {
        int l = idx / (2 * D * D);
        int r = idx % (2 * D * D);
        int n = r >> 7, k = r & 127;
        w1t[idx] = (half_t)loadF(W1, (long long)l * 2 * D * D + (long long)k * 256 + n, isf32);
    } else if (idx < 2 * per) {
        int j = idx - per;
        int l = j / (2 * D * D);
        int r = j % (2 * D * D);
        int n = r >> 8, k = r & 255;
        w2t[j] = (half_t)loadF(W2, (long long)l * 2 * D * D + (long long)k * D + n, isf32);
    }
}

// ---------------- CSR build ----------------
__global__ void hist_k(const int* __restrict__ ei, int* __restrict__ deg) {
    int e = blockIdx.x * 256 + threadIdx.x;
    if (e < NE) atomicAdd(&deg[ei[NE + e]], 1);
}

__global__ void scan1_k(const int* __restrict__ deg, int* __restrict__ tmp,
                        int* __restrict__ partial) {
    __shared__ int s[256];
    int t = threadIdx.x;
    int i = blockIdx.x * 256 + t;
    int v = (i < NN) ? deg[i] : 0;
    s[t] = v;
    __syncthreads();
    for (int off = 1; off < 256; off <<= 1) {
        int x = (t >= off) ? s[t - off] : 0;
        __syncthreads();
        s[t] += x;
        __syncthreads();
    }
    if (i < NN) tmp[i] = s[t];
    if (t == 255) partial[blockIdx.x] = s[255];
}

__global__ void scan2_k(int* __restrict__ partial, int nb) {
    __shared__ int s[256];
    int t = threadIdx.x;
    int v = (t < nb) ? partial[t] : 0;
    s[t] = v;
    __syncthreads();
    for (int off = 1; off < 256; off <<= 1) {
        int x = (t >= off) ? s[t - off] : 0;
        __syncthreads();
        s[t] += x;
        __syncthreads();
    }
    int excl = s[t] - v;
    __syncthreads();
    if (t < nb) partial[t] = excl;
}

__global__ void scan3_k(const int* __restrict__ tmp, const int* __restrict__ partial,
                        const int* __restrict__ deg,
                        int* __restrict__ row_start, int* __restrict__ next) {
    int i = blockIdx.x * 256 + threadIdx.x;
    if (i >= NN) return;
    int incl = tmp[i] + partial[i >> 8];
    row_start[i + 1] = incl;
    next[i] = incl - deg[i];
    if (i == 0) row_start[0] = 0;
}

__global__ void fill_k(const int* __restrict__ ei, const int* __restrict__ ea,
                       int* __restrict__ next, int* __restrict__ csr) {
    int e = blockIdx.x * 256 + threadIdx.x;
    if (e >= NE) return;
    int src = ei[e];
    int dst = ei[NE + e];
    int c = ea[2 * e] * 4 + ea[2 * e + 1];
    int pos = atomicAdd(&next[dst], 1);
    csr[pos] = src | (c << 16);
}

// ---------------- forward ----------------
__global__ void embed_k(const int* __restrict__ x,
                        const void* __restrict__ atom,
                        const void* __restrict__ chir,
                        const void* __restrict__ hyb,
                        const int* __restrict__ fl,
                        half_t* __restrict__ hpost) {
    int isf32 = *fl;
    int idx = blockIdx.x * 256 + threadIdx.x;   // over NN*64
    if (idx >= NN * 64) return;
    int n = idx >> 6, fp = (idx & 63) * 2;
    long long i0 = (long long)x[n * 3 + 0] * D + fp;
    long long i1 = (long long)x[n * 3 + 1] * D + fp;
    long long i2 = (long long)x[n * 3 + 2] * D + fp;
    float v0 = loadF(atom, i0, isf32) + loadF(chir, i1, isf32) + loadF(hyb, i2, isf32);
    float v1 = loadF(atom, i0 + 1, isf32) + loadF(chir, i1 + 1, isf32) + loadF(hyb, i2 + 1, isf32);
    half_t* dst = hpost + (long long)n * D + fp;
    dst[0] = (half_t)v0;
    dst[1] = (half_t)v1;
}

// one wave per node, unroll-4 gather with 2 independent accumulator pairs
__global__ __launch_bounds__(256) void aggr_k(
        const half_t* __restrict__ h,
        const int* __restrict__ row_start,
        const int* __restrict__ csr,
        const void* __restrict__ e1, const void* __restrict__ e2,
        const int* __restrict__ fl, int layer,
        float* __restrict__ agg) {
    __shared__ float comb[24 * D];
    int isf32 = *fl;
    long long e1off = (long long)layer * 6 * D;
    long long e2off = (long long)layer * 4 * D;
    for (int i = threadIdx.x; i < 24 * D; i += 256) {
        int c = i >> 7, f = i & 127;
        comb[i] = loadF(e1, e1off + (c >> 2) * D + f, isf32) +
                  loadF(e2, e2off + (c & 3) * D + f, isf32);
    }
    __syncthreads();
    int n = blockIdx.x * 4 + (threadIdx.x >> 6);
    int lane = threadIdx.x & 63;
    const f32x2* comb2 = (const f32x2*)comb;
    int beg = row_start[n], end = row_start[n + 1];
    float va0 = 0.f, va1 = 0.f, vb0 = 0.f, vb1 = 0.f;
    int i = beg;
    for (; i + 3 < end; i += 4) {
        int pk0 = csr[i], pk1 = csr[i + 1], pk2 = csr[i + 2], pk3 = csr[i + 3];
        unsigned g0 = *(const unsigned*)(h + (long long)(pk0 & 0xFFFF) * D + 2 * lane);
        unsigned g1 = *(const unsigned*)(h + (long long)(pk1 & 0xFFFF) * D + 2 * lane);
        unsigned g2 = *(const unsigned*)(h + (long long)(pk2 & 0xFFFF) * D + 2 * lane);
        unsigned g3 = *(const unsigned*)(h + (long long)(pk3 & 0xFFFF) * D + 2 * lane);
        f32x2 c0 = comb2[(pk0 >> 16) * 64 + lane];
        f32x2 c1 = comb2[(pk1 >> 16) * 64 + lane];
        f32x2 c2 = comb2[(pk2 >> 16) * 64 + lane];
        f32x2 c3 = comb2[(pk3 >> 16) * 64 + lane];
        va0 += (float)((const half_t*)&g0)[0] + c0.x;
        va1 += (float)((const half_t*)&g0)[1] + c0.y;
        vb0 += (float)((const half_t*)&g1)[0] + c1.x;
        vb1 += (float)((const half_t*)&g1)[1] + c1.y;
        va0 += (float)((const half_t*)&g2)[0] + c2.x;
        va1 += (float)((const half_t*)&g2)[1] + c2.y;
        vb0 += (float)((const half_t*)&g3)[0] + c3.x;
        vb1 += (float)((const half_t*)&g3)[1] + c3.y;
    }
    for (; i < end; ++i) {
        int pk = csr[i];
        unsigned gv = *(const unsigned*)(h + (long long)(pk & 0xFFFF) * D + 2 * lane);
        f32x2 cc = comb2[(pk >> 16) * 64 + lane];
        va0 += (float)((const half_t*)&gv)[0] + cc.x;
        va1 += (float)((const half_t*)&gv)[1] + cc.y;
    }
    f32x2 out; out.x = va0 + vb0; out.y = va1 + vb1;
    *(f32x2*)(agg + (long long)n * D + 2 * lane) = out;
}

// Fused MLP, fp16 MFMA, B operands DIRECT from global (L1-resident; all 4
// waves share the same B fragments). LDS only for the mid C->A transpose.
__global__ __launch_bounds__(256) void mlp_k(
        const float* __restrict__ agg,
        const half_t* __restrict__ w1t, const half_t* __restrict__ w2t,
        const void* __restrict__ b1, const void* __restrict__ b2,
        const int* __restrict__ fl, int layer,
        half_t* __restrict__ h2, float* __restrict__ stats) {
    __shared__ ushort_t Ms[64 * 72];   // mid chunk [m][k], fp16 bits
    __shared__ float SS[2 * D];
    int isf32 = *fl;
    int m0 = blockIdx.x * 64;
    long long b1off = (long long)layer * 2 * D;
    long long b2off = (long long)layer * D;
    int tid = threadIdx.x;
    int w = tid >> 6, lane = tid & 63;
    int quad = lane >> 4, l16 = lane & 15;
    SS[tid] = 0.f;

    // A fragments direct from global (reused across all 4 N-chunks)
    int arow = m0 + w * 16 + l16;
    if (arow >= NN) arow = NN - 1;
    const float* ap = agg + (long long)arow * D + quad * 8;
    half8 afrag[4];
#pragma unroll
    for (int kk4 = 0; kk4 < 4; ++kk4) {
        f32x4 u0 = *(const f32x4*)(ap + kk4 * 32);
        f32x4 u1 = *(const f32x4*)(ap + kk4 * 32 + 4);
#pragma unroll
        for (int j = 0; j < 4; ++j) {
            afrag[kk4][j] = (half_t)u0[j];
            afrag[kk4][4 + j] = (half_t)u1[j];
        }
    }

    const half_t* w1p = w1t + (long long)layer * 256 * 128;
    const half_t* w2p = w2t + (long long)layer * 128 * 256;
    f32x4 acc[8];
#pragma unroll
    for (int t = 0; t < 8; ++t) acc[t] = (f32x4){0.f, 0.f, 0.f, 0.f};

    for (int nc = 0; nc < 4; ++nc) {
        // gemm1 chunk: 64 rows x 64 cols, B direct from global
        f32x4 macc[4];
#pragma unroll
        for (int nt = 0; nt < 4; ++nt) macc[nt] = (f32x4){0.f, 0.f, 0.f, 0.f};
#pragma unroll
        for (int kk4 = 0; kk4 < 4; ++kk4) {
            half8 a = afrag[kk4];
#pragma unroll
            for (int nt = 0; nt < 4; ++nt) {
                half8 b = *(const half8*)(w1p + (long long)(nc * 64 + nt * 16 + l16) * 128
                                              + kk4 * 32 + quad * 8);
                macc[nt] = __builtin_amdgcn_mfma_f32_16x16x32_f16(a, b, macc[nt], 0, 0, 0);
            }
        }
        __syncthreads();  // prev-iter gemm2's Ms reads complete (no-op cost nc=0)
        // bias + relu -> Ms (C-layout -> A-layout via LDS)
#pragma unroll
        for (int nt = 0; nt < 4; ++nt) {
            float bias = loadF(b1, b1off + nc * 64 + nt * 16 + l16, isf32);
#pragma unroll
            for (int r = 0; r < 4; ++r) {
                float v = fmaxf(macc[nt][r] + bias, 0.f);
                half_t hv = (half_t)v;
                Ms[(w * 16 + quad * 4 + r) * 72 + nt * 16 + l16] = *(ushort_t*)&hv;
            }
        }
        __syncthreads();  // Ms visible
        // gemm2 partial: acc += mid_chunk @ W2_chunk, B2 direct from global
#pragma unroll
        for (int kk4 = 0; kk4 < 2; ++kk4) {
            half8 a = *(const half8*)&Ms[(w * 16 + l16) * 72 + kk4 * 32 + quad * 8];
#pragma unroll
            for (int t = 0; t < 8; ++t) {
                half8 b = *(const half8*)(w2p + (long long)((t >> 2) * 64 + (t & 3) * 16 + l16) * 256
                                              + nc * 64 + kk4 * 32 + quad * 8);
                acc[t] = __builtin_amdgcn_mfma_f32_16x16x32_f16(a, b, acc[t], 0, 0, 0);
            }
        }
    }
    // epilogue: bias, fp16 store, stats block-reduce
#pragma unroll
    for (int t = 0; t < 8; ++t) {
        int col = (t >> 2) * 64 + (t & 3) * 16 + l16;
        float bias = loadF(b2, b2off + col, isf32);
        float s = 0.f, q = 0.f;
#pragma unroll
        for (int r = 0; r < 4; ++r) {
            int row = m0 + w * 16 + quad * 4 + r;
            if (row < NN) {
                float v = acc[t][r] + bias;
                h2[(long long)row * D + col] = (half_t)v;
                s += v; q += v * v;
            }
        }
        atomicAdd(&SS[col], s);
        atomicAdd(&SS[D + col], q);
    }
    __syncthreads();
    atomicAdd(&stats[tid], SS[tid]);
}

__global__ void finalize_k(float* __restrict__ stats,
                           const void* __restrict__ gamma,
                           const void* __restrict__ beta,
                           const int* __restrict__ fl, int layer,
                           float* __restrict__ norm) {
    int isf32 = *fl;
    int t = threadIdx.x;
    if (t < D) {
        float mu = stats[t] * (1.f / NN);
        float var = fmaxf(stats[D + t] * (1.f / NN) - mu * mu, 0.f);
        float rs = rsqrtf(var + 1e-5f);
        float sc = rs * loadF(gamma, (long long)layer * D + t, isf32);
        float sh = loadF(beta, (long long)layer * D + t, isf32) - mu * sc;
        norm[t] = sc;
        norm[D + t] = sh;
    }
    stats[t] = 0.f;
}

__global__ void bnapply_k(const half_t* __restrict__ h2,
                          const float* __restrict__ norm,
                          half_t* __restrict__ hpost,
                          float* __restrict__ out,
                          int relu) {
    int idx = blockIdx.x * 256 + threadIdx.x;  // over NN*64
    if (idx >= NN * 64) return;
    int fp = (idx & 63) * 2;
    unsigned hv = *(const unsigned*)(h2 + (long long)(idx >> 6) * D + fp);
    float v0 = fmaf((float)((const half_t*)&hv)[0], norm[fp], norm[D + fp]);
    float v1 = fmaf((float)((const half_t*)&hv)[1], norm[fp + 1], norm[D + fp + 1]);
    if (relu) { v0 = fmaxf(v0, 0.f); v1 = fmaxf(v1, 0.f); }
    if (out) {
        f32x2 o; o.x = v0; o.y = v1;
        *(f32x2*)(out + (long long)(idx >> 6) * D + fp) = o;
    } else {
        half_t* dst = hpost + (long long)(idx >> 6) * D + fp;
        dst[0] = (half_t)v0;
        dst[1] = (half_t)v1;
    }
}

extern "C" void kernel_launch(void* const* d_in, const int* in_sizes, int n_in,
                              void* d_out, int out_size, void* d_ws, size_t ws_size,
                              hipStream_t stream) {
    const int* x     = (const int*)d_in[0];
    const int* ei    = (const int*)d_in[1];
    const int* ea    = (const int*)d_in[2];
    const void* atom = d_in[3];
    const void* chir = d_in[4];
    const void* hyb  = d_in[5];
    const void* e1   = d_in[6];
    const void* e2   = d_in[7];
    const void* W1   = d_in[8];
    const void* b1   = d_in[9];
    const void* W2   = d_in[10];
    const void* b2   = d_in[11];
    const void* gm   = d_in[12];
    const void* bt   = d_in[13];

    const size_t ND = (size_t)NN * D;

    char* base = (char*)d_ws;
    float* stats   = (float*)base;
    float* norm    = (float*)(base + 1024);
    int*   flag    = (int*)(base + 2048);
    char*  p       = base + 4096;
    half_t* hpost  = (half_t*)p;  p += ND * 2;
    half_t* h2     = (half_t*)p;  p += ND * 2;
    half_t* w1t    = (half_t*)p;  p += (size_t)NL * 2 * D * D * 2;
    half_t* w2t    = (half_t*)p;  p += (size_t)NL * 2 * D * D * 2;
    int* csr       = (int*)p;     p += (size_t)NE * 4;
    int* row_start = (int*)p;     p += (size_t)(NN + 1) * 4 + 12;
    int* deg       = (int*)p;     p += (size_t)NN * 4;
    int* tmp       = (int*)p;     p += (size_t)NN * 4;
    int* next      = (int*)p;     p += (size_t)NN * 4;
    int* partial   = (int*)p;

    float* aggbuf = (float*)d_out;  // f32 scratch; final bnapply overwrites at end

    const int N2_BLOCKS = (NN * 64 + 255) / 256;  // 12500
    const int E_BLOCKS  = (NE + 255) / 256;       // 2344
    const int N_BLOCKS  = (NN + 255) / 256;       // 196
    const int M_TILES   = (NN + 63) / 64;         // 782
    const int PW_BLOCKS = (2 * NL * 2 * D * D + 255) / 256;  // 1280

    detect_k<<<1, 256, 0, stream>>>(atom, flag);
    prepw_k<<<PW_BLOCKS, 256, 0, stream>>>(W1, W2, flag, w1t, w2t);

    zero_i<<<N_BLOCKS, 256, 0, stream>>>(deg, NN);
    hist_k<<<E_BLOCKS, 256, 0, stream>>>(ei, deg);
    scan1_k<<<N_BLOCKS, 256, 0, stream>>>(deg, tmp, partial);
    scan2_k<<<1, 256, 0, stream>>>(partial, N_BLOCKS);
    scan3_k<<<N_BLOCKS, 256, 0, stream>>>(tmp, partial, deg, row_start, next);
    fill_k<<<E_BLOCKS, 256, 0, stream>>>(ei, ea, next, csr);

    embed_k<<<N2_BLOCKS, 256, 0, stream>>>(x, atom, chir, hyb, flag, hpost);
    zero_f<<<1, 256, 0, stream>>>(stats, 2 * D);

    for (int l = 0; l < NL; ++l) {
        aggr_k<<<NN / 4, 256, 0, stream>>>(hpost, row_start, csr, e1, e2, flag, l, aggbuf);
        mlp_k<<<M_TILES, 256, 0, stream>>>(aggbuf, w1t, w2t, b1, b2, flag, l, h2, stats);
        finalize_k<<<1, 256, 0, stream>>>(stats, gm, bt, flag, l, norm);
        int last = (l == NL - 1);
        bnapply_k<<<N2_BLOCKS, 256, 0, stream>>>(h2, norm,
            hpost, last ? (float*)d_out : (float*)nullptr, last ? 0 : 1);
    }
}

// Round 11
// 748.756 us; speedup vs baseline: 1.2545x; 1.2545x over previous
//
#include <hip/hip_runtime.h>
#include <hip/hip_bf16.h>

#define NN 50000
#define NE 600000
#define D 128
#define NL 5

typedef __hip_bfloat16 bf16;
typedef unsigned short ushort_t;
typedef _Float16 half_t;
typedef __attribute__((ext_vector_type(8))) _Float16 half8;
typedef __attribute__((ext_vector_type(8))) short short8;
typedef __attribute__((ext_vector_type(4))) float f32x4;
typedef __attribute__((ext_vector_type(2))) float f32x2;

__device__ __forceinline__ float b2f(bf16 v) { return __bfloat162float(v); }

__device__ __forceinline__ float loadF(const void* p, long long i, int isf32) {
    if (isf32) return ((const float*)p)[i];
    return b2f(((const bf16*)p)[i]);
}

__global__ void detect_k(const void* __restrict__ atom, int* __restrict__ flag) {
    __shared__ int vote;
    if (threadIdx.x == 0) vote = 0;
    __syncthreads();
    unsigned short u = ((const unsigned short*)atom)[threadIdx.x];
    unsigned short ex = (u >> 7) & 0xFF;
    if (ex >= 0x90) atomicOr(&vote, 1);
    __syncthreads();
    if (threadIdx.x == 0) *flag = vote;
}

__global__ void zero_f(float* __restrict__ p, int n) {
    int i = blockIdx.x * 256 + threadIdx.x;
    if (i < n) p[i] = 0.f;
}
__global__ void zero_i(int* __restrict__ p, int n) {
    int i = blockIdx.x * 256 + threadIdx.x;
    if (i < n) p[i] = 0;
}
// identity norm: scale=1, shift=0
__global__ void initnorm_k(float* __restrict__ norm) {
    int t = threadIdx.x;
    norm[t] = (t < D) ? 1.f : 0.f;
}

// convert + transpose weights to fp16 once per launch
__global__ void prepw_k(const void* __restrict__ W1, const void* __restrict__ W2,
                        const int* __restrict__ fl,
                        half_t* __restrict__ w1t, half_t* __restrict__ w2t) {
    int isf32 = *fl;
    int idx = blockIdx.x * 256 + threadIdx.x;
    const int per = NL * 2 * D * D;
    if (idx < per) {
        int l = idx / (2 * D * D);
        int r = idx % (2 * D * D);
        int n = r >> 7, k = r & 127;
        w1t[idx] = (half_t)loadF(W1, (long long)l * 2 * D * D + (long long)k * 256 + n, isf32);
    } else if (idx < 2 * per) {
        int j = idx - per;
        int l = j / (2 * D * D);
        int r = j % (2 * D * D);
        int n = r >> 8, k = r & 255;
        w2t[j] = (half_t)loadF(W2, (long long)l * 2 * D * D + (long long)k * D + n, isf32);
    }
}

// ---------------- CSR build ----------------
__global__ void hist_k(const int* __restrict__ ei, int* __restrict__ deg) {
    int e = blockIdx.x * 256 + threadIdx.x;
    if (e < NE) atomicAdd(&deg[ei[NE + e]], 1);
}

__global__ void scan1_k(const int* __restrict__ deg, int* __restrict__ tmp,
                        int* __restrict__ partial) {
    __shared__ int s[256];
    int t = threadIdx.x;
    int i = blockIdx.x * 256 + t;
    int v = (i < NN) ? deg[i] : 0;
    s[t] = v;
    __syncthreads();
    for (int off = 1; off < 256; off <<= 1) {
        int x = (t >= off) ? s[t - off] : 0;
        __syncthreads();
        s[t] += x;
        __syncthreads();
    }
    if (i < NN) tmp[i] = s[t];
    if (t == 255) partial[blockIdx.x] = s[255];
}

__global__ void scan2_k(int* __restrict__ partial, int nb) {
    __shared__ int s[256];
    int t = threadIdx.x;
    int v = (t < nb) ? partial[t] : 0;
    s[t] = v;
    __syncthreads();
    for (int off = 1; off < 256; off <<= 1) {
        int x = (t >= off) ? s[t - off] : 0;
        __syncthreads();
        s[t] += x;
        __syncthreads();
    }
    int excl = s[t] - v;
    __syncthreads();
    if (t < nb) partial[t] = excl;
}

__global__ void scan3_k(const int* __restrict__ tmp, const int* __restrict__ partial,
                        const int* __restrict__ deg,
                        int* __restrict__ row_start, int* __restrict__ next) {
    int i = blockIdx.x * 256 + threadIdx.x;
    if (i >= NN) return;
    int incl = tmp[i] + partial[i >> 8];
    row_start[i + 1] = incl;
    next[i] = incl - deg[i];
    if (i == 0) row_start[0] = 0;
}

__global__ void fill_k(const int* __restrict__ ei, const int* __restrict__ ea,
                       int* __restrict__ next, int* __restrict__ csr) {
    int e = blockIdx.x * 256 + threadIdx.x;
    if (e >= NE) return;
    int src = ei[e];
    int dst = ei[NE + e];
    int c = ea[2 * e] * 4 + ea[2 * e + 1];
    int pos = atomicAdd(&next[dst], 1);
    csr[pos] = src | (c << 16);
}

// ---------------- forward ----------------
// embedding -> raw fp16 h2 (identity norm applied by layer-0 aggr)
__global__ void embed_k(const int* __restrict__ x,
                        const void* __restrict__ atom,
                        const void* __restrict__ chir,
                        const void* __restrict__ hyb,
                        const int* __restrict__ fl,
                        half_t* __restrict__ h2) {
    int isf32 = *fl;
    int idx = blockIdx.x * 256 + threadIdx.x;   // over NN*64
    if (idx >= NN * 64) return;
    int n = idx >> 6, fp = (idx & 63) * 2;
    long long i0 = (long long)x[n * 3 + 0] * D + fp;
    long long i1 = (long long)x[n * 3 + 1] * D + fp;
    long long i2 = (long long)x[n * 3 + 2] * D + fp;
    float v0 = loadF(atom, i0, isf32) + loadF(chir, i1, isf32) + loadF(hyb, i2, isf32);
    float v1 = loadF(atom, i0 + 1, isf32) + loadF(chir, i1 + 1, isf32) + loadF(hyb, i2 + 1, isf32);
    half_t* dst = h2 + (long long)n * D + fp;
    dst[0] = (half_t)v0;
    dst[1] = (half_t)v1;
}

// one wave per node; half-wave edge-pairing (lane loads 4 feats = 8B; lanes
// 0-31 take even edge, 32-63 odd edge). BN(scale,shift)+ReLU applied to each
// gathered value (h is raw pre-BN h2). agg[n,:] = sum_e BNrelu(h[src,:]) + comb
__global__ __launch_bounds__(256) void aggr_k(
        const half_t* __restrict__ h,
        const float* __restrict__ norm,
        const int* __restrict__ row_start,
        const int* __restrict__ csr,
        const void* __restrict__ e1, const void* __restrict__ e2,
        const int* __restrict__ fl, int layer, int relu,
        float* __restrict__ agg) {
    __shared__ float comb[24 * D];
    int isf32 = *fl;
    long long e1off = (long long)layer * 6 * D;
    long long e2off = (long long)layer * 4 * D;
    for (int i = threadIdx.x; i < 24 * D; i += 256) {
        int c = i >> 7, f = i & 127;
        comb[i] = loadF(e1, e1off + (c >> 2) * D + f, isf32) +
                  loadF(e2, e2off + (c & 3) * D + f, isf32);
    }
    __syncthreads();
    int n = blockIdx.x * 4 + (threadIdx.x >> 6);
    int lane = threadIdx.x & 63;
    int hh = lane >> 5;              // half-wave id
    int f4 = (lane & 31) * 4;        // features f4..f4+3
    float sc[4], sh[4];
#pragma unroll
    for (int j = 0; j < 4; ++j) { sc[j] = norm[f4 + j]; sh[j] = norm[D + f4 + j]; }
    int beg = row_start[n], end = row_start[n + 1];
    float va[4] = {0.f, 0.f, 0.f, 0.f};
    float vb[4] = {0.f, 0.f, 0.f, 0.f};
    int i = beg;
    for (; i + 3 < end; i += 4) {
        int pkA = csr[i + hh];
        int pkB = csr[i + 2 + hh];
        unsigned long long gA = *(const unsigned long long*)(h + (long long)(pkA & 0xFFFF) * D + f4);
        unsigned long long gB = *(const unsigned long long*)(h + (long long)(pkB & 0xFFFF) * D + f4);
        f32x4 cA = *(const f32x4*)&comb[(pkA >> 16) * D + f4];
        f32x4 cB = *(const f32x4*)&comb[(pkB >> 16) * D + f4];
        const half_t* ga = (const half_t*)&gA;
        const half_t* gb = (const half_t*)&gB;
#pragma unroll
        for (int j = 0; j < 4; ++j) {
            float a = fmaf((float)ga[j], sc[j], sh[j]);
            float b = fmaf((float)gb[j], sc[j], sh[j]);
            if (relu) { a = fmaxf(a, 0.f); b = fmaxf(b, 0.f); }
            va[j] += a + cA[j];
            vb[j] += b + cB[j];
        }
    }
    for (; i + 1 < end; i += 2) {
        int pk = csr[i + hh];
        unsigned long long g = *(const unsigned long long*)(h + (long long)(pk & 0xFFFF) * D + f4);
        f32x4 c = *(const f32x4*)&comb[(pk >> 16) * D + f4];
        const half_t* gh = (const half_t*)&g;
#pragma unroll
        for (int j = 0; j < 4; ++j) {
            float a = fmaf((float)gh[j], sc[j], sh[j]);
            if (relu) a = fmaxf(a, 0.f);
            va[j] += a + c[j];
        }
    }
    if (i < end && hh == 0) {   // lone edge -> half 0
        int pk = csr[i];
        unsigned long long g = *(const unsigned long long*)(h + (long long)(pk & 0xFFFF) * D + f4);
        f32x4 c = *(const f32x4*)&comb[(pk >> 16) * D + f4];
        const half_t* gh = (const half_t*)&g;
#pragma unroll
        for (int j = 0; j < 4; ++j) {
            float a = fmaf((float)gh[j], sc[j], sh[j]);
            if (relu) a = fmaxf(a, 0.f);
            va[j] += a + c[j];
        }
    }
#pragma unroll
    for (int j = 0; j < 4; ++j) {
        float v = va[j] + vb[j];
        v += __shfl_down(v, 32, 64);
        va[j] = v;
    }
    if (hh == 0) {
        f32x4 o; o.x = va[0]; o.y = va[1]; o.z = va[2]; o.w = va[3];
        *(f32x4*)(agg + (long long)n * D + f4) = o;
    }
}

// Fused MLP (R9 structure): fp16 MFMA, B chunks staged in LDS, mid in LDS.
// Writes raw pre-BN h2 (fp16) + per-feature stats.
__global__ __launch_bounds__(256) void mlp_k(
        const float* __restrict__ agg,
        const half_t* __restrict__ w1t, const half_t* __restrict__ w2t,
        const void* __restrict__ b1, const void* __restrict__ b2,
        const int* __restrict__ fl, int layer,
        half_t* __restrict__ h2, float* __restrict__ stats) {
    __shared__ ushort_t Bs[9216];      // B1 chunk [64][136] / B2 chunk [128][72]
    __shared__ ushort_t Ms[64 * 72];   // mid chunk [m][k], fp16 bits
    __shared__ float SS[2 * D];
    int isf32 = *fl;
    int m0 = blockIdx.x * 64;
    long long b1off = (long long)layer * 2 * D;
    long long b2off = (long long)layer * D;
    int tid = threadIdx.x;
    int w = tid >> 6, lane = tid & 63;
    int quad = lane >> 4, l16 = lane & 15;
    SS[tid] = 0.f;

    int arow = m0 + w * 16 + l16;
    if (arow >= NN) arow = NN - 1;
    const float* ap = agg + (long long)arow * D + quad * 8;
    half8 afrag[4];
#pragma unroll
    for (int kk4 = 0; kk4 < 4; ++kk4) {
        f32x4 u0 = *(const f32x4*)(ap + kk4 * 32);
        f32x4 u1 = *(const f32x4*)(ap + kk4 * 32 + 4);
#pragma unroll
        for (int j = 0; j < 4; ++j) {
            afrag[kk4][j] = (half_t)u0[j];
            afrag[kk4][4 + j] = (half_t)u1[j];
        }
    }

    const half_t* w1p = w1t + (long long)layer * 256 * 128;
    const half_t* w2p = w2t + (long long)layer * 128 * 256;
    f32x4 acc[8];
#pragma unroll
    for (int t = 0; t < 8; ++t) acc[t] = (f32x4){0.f, 0.f, 0.f, 0.f};

    for (int nc = 0; nc < 4; ++nc) {
        __syncthreads();  // prev-iter Bs(B2)/Ms reads done
        {   // stage B1 chunk
            int r = tid >> 2, kq = (tid & 3) * 32;
            const ushort_t* src = (const ushort_t*)(w1p + (long long)(nc * 64 + r) * 128 + kq);
            ushort_t* dst = &Bs[r * 136 + kq];
#pragma unroll
            for (int t = 0; t < 4; ++t)
                *(short8*)(dst + t * 8) = *(const short8*)(src + t * 8);
        }
        __syncthreads();
        f32x4 macc[4];
#pragma unroll
        for (int nt = 0; nt < 4; ++nt) macc[nt] = (f32x4){0.f, 0.f, 0.f, 0.f};
#pragma unroll
        for (int kk4 = 0; kk4 < 4; ++kk4) {
            half8 a = afrag[kk4];
#pragma unroll
            for (int nt = 0; nt < 4; ++nt) {
                half8 b = *(const half8*)&Bs[(nt * 16 + l16) * 136 + kk4 * 32 + quad * 8];
                macc[nt] = __builtin_amdgcn_mfma_f32_16x16x32_f16(a, b, macc[nt], 0, 0, 0);
            }
        }
#pragma unroll
        for (int nt = 0; nt < 4; ++nt) {
            float bias = loadF(b1, b1off + nc * 64 + nt * 16 + l16, isf32);
#pragma unroll
            for (int r = 0; r < 4; ++r) {
                float v = fmaxf(macc[nt][r] + bias, 0.f);
                half_t hv = (half_t)v;
                Ms[(w * 16 + quad * 4 + r) * 72 + nt * 16 + l16] = *(ushort_t*)&hv;
            }
        }
        __syncthreads();  // gemm1 Bs reads + Ms writes done
        {   // stage B2 chunk
            int r = tid >> 1, kq = (tid & 1) * 32;
            const ushort_t* src = (const ushort_t*)(w2p + (long long)r * 256 + nc * 64 + kq);
            ushort_t* dst = &Bs[r * 72 + kq];
#pragma unroll
            for (int t = 0; t < 4; ++t)
                *(short8*)(dst + t * 8) = *(const short8*)(src + t * 8);
        }
        __syncthreads();
#pragma unroll
        for (int kk4 = 0; kk4 < 2; ++kk4) {
            half8 a = *(const half8*)&Ms[(w * 16 + l16) * 72 + kk4 * 32 + quad * 8];
#pragma unroll
            for (int t = 0; t < 8; ++t) {
                half8 b = *(const half8*)&Bs[((t >> 2) * 64 + (t & 3) * 16 + l16) * 72 + kk4 * 32 + quad * 8];
                acc[t] = __builtin_amdgcn_mfma_f32_16x16x32_f16(a, b, acc[t], 0, 0, 0);
            }
        }
    }
#pragma unroll
    for (int t = 0; t < 8; ++t) {
        int col = (t >> 2) * 64 + (t & 3) * 16 + l16;
        float bias = loadF(b2, b2off + col, isf32);
        float s = 0.f, q = 0.f;
#pragma unroll
        for (int r = 0; r < 4; ++r) {
            int row = m0 + w * 16 + quad * 4 + r;
            if (row < NN) {
                float v = acc[t][r] + bias;
                h2[(long long)row * D + col] = (half_t)v;
                s += v; q += v * v;
            }
        }
        atomicAdd(&SS[col], s);
        atomicAdd(&SS[D + col], q);
    }
    __syncthreads();
    atomicAdd(&stats[tid], SS[tid]);
}

__global__ void finalize_k(float* __restrict__ stats,
                           const void* __restrict__ gamma,
                           const void* __restrict__ beta,
                           const int* __restrict__ fl, int layer,
                           float* __restrict__ norm) {
    int isf32 = *fl;
    int t = threadIdx.x;
    if (t < D) {
        float mu = stats[t] * (1.f / NN);
        float var = fmaxf(stats[D + t] * (1.f / NN) - mu * mu, 0.f);
        float rs = rsqrtf(var + 1e-5f);
        float sc = rs * loadF(gamma, (long long)layer * D + t, isf32);
        float sh = loadF(beta, (long long)layer * D + t, isf32) - mu * sc;
        norm[t] = sc;
        norm[D + t] = sh;
    }
    stats[t] = 0.f;
}

// final output: out = scale*h2 + shift (f32)
__global__ void apply_k(const half_t* __restrict__ h2,
                        const float* __restrict__ norm,
                        float* __restrict__ out) {
    int idx = blockIdx.x * 256 + threadIdx.x;  // over NN*64
    if (idx >= NN * 64) return;
    int fp = (idx & 63) * 2;
    unsigned hv = *(const unsigned*)(h2 + (long long)(idx >> 6) * D + fp);
    float v0 = fmaf((float)((const half_t*)&hv)[0], norm[fp], norm[D + fp]);
    float v1 = fmaf((float)((const half_t*)&hv)[1], norm[fp + 1], norm[D + fp + 1]);
    f32x2 o; o.x = v0; o.y = v1;
    *(f32x2*)(out + (long long)(idx >> 6) * D + fp) = o;
}

extern "C" void kernel_launch(void* const* d_in, const int* in_sizes, int n_in,
                              void* d_out, int out_size, void* d_ws, size_t ws_size,
                              hipStream_t stream) {
    const int* x     = (const int*)d_in[0];
    const int* ei    = (const int*)d_in[1];
    const int* ea    = (const int*)d_in[2];
    const void* atom = d_in[3];
    const void* chir = d_in[4];
    const void* hyb  = d_in[5];
    const void* e1   = d_in[6];
    const void* e2   = d_in[7];
    const void* W1   = d_in[8];
    const void* b1   = d_in[9];
    const void* W2   = d_in[10];
    const void* b2   = d_in[11];
    const void* gm   = d_in[12];
    const void* bt   = d_in[13];

    const size_t ND = (size_t)NN * D;

    char* base = (char*)d_ws;
    float* stats   = (float*)base;
    float* norm    = (float*)(base + 1024);
    int*   flag    = (int*)(base + 2048);
    char*  p       = base + 4096;
    half_t* h2     = (half_t*)p;  p += ND * 2;
    half_t* w1t    = (half_t*)p;  p += (size_t)NL * 2 * D * D * 2;
    half_t* w2t    = (half_t*)p;  p += (size_t)NL * 2 * D * D * 2;
    int* csr       = (int*)p;     p += (size_t)NE * 4;
    int* row_start = (int*)p;     p += (size_t)(NN + 1) * 4 + 12;
    int* deg       = (int*)p;     p += (size_t)NN * 4;
    int* tmp       = (int*)p;     p += (size_t)NN * 4;
    int* next      = (int*)p;     p += (size_t)NN * 4;
    int* partial   = (int*)p;

    float* aggbuf = (float*)d_out;  // f32 scratch; apply_k overwrites at end

    const int N2_BLOCKS = (NN * 64 + 255) / 256;  // 12500
    const int E_BLOCKS  = (NE + 255) / 256;       // 2344
    const int N_BLOCKS  = (NN + 255) / 256;       // 196
    const int M_TILES   = (NN + 63) / 64;         // 782
    const int PW_BLOCKS = (2 * NL * 2 * D * D + 255) / 256;  // 1280

    detect_k<<<1, 256, 0, stream>>>(atom, flag);
    prepw_k<<<PW_BLOCKS, 256, 0, stream>>>(W1, W2, flag, w1t, w2t);

    zero_i<<<N_BLOCKS, 256, 0, stream>>>(deg, NN);
    hist_k<<<E_BLOCKS, 256, 0, stream>>>(ei, deg);
    scan1_k<<<N_BLOCKS, 256, 0, stream>>>(deg, tmp, partial);
    scan2_k<<<1, 256, 0, stream>>>(partial, N_BLOCKS);
    scan3_k<<<N_BLOCKS, 256, 0, stream>>>(tmp, partial, deg, row_start, next);
    fill_k<<<E_BLOCKS, 256, 0, stream>>>(ei, ea, next, csr);

    embed_k<<<N2_BLOCKS, 256, 0, stream>>>(x, atom, chir, hyb, flag, h2);
    initnorm_k<<<1, 256, 0, stream>>>(norm);
    zero_f<<<1, 256, 0, stream>>>(stats, 2 * D);

    for (int l = 0; l < NL; ++l) {
        aggr_k<<<NN / 4, 256, 0, stream>>>(h2, norm, row_start, csr,
                                           e1, e2, flag, l, (l > 0) ? 1 : 0, aggbuf);
        mlp_k<<<M_TILES, 256, 0, stream>>>(aggbuf, w1t, w2t, b1, b2, flag, l, h2, stats);
        finalize_k<<<1, 256, 0, stream>>>(stats, gm, bt, flag, l, norm);
    }
    apply_k<<<N2_BLOCKS, 256, 0, stream>>>(h2, norm, (float*)d_out);
}